// Round 6
// baseline (18554.285 us; speedup 1.0000x reference)
//
#include <hip/hip_runtime.h>
#include <math.h>

// LSTM B=128,T=1024,D=64,H=256,C=6 — xg-precompute + single-CU-per-batch.
//
// Stage 1 (xg_gemm): xg[b,t,:] = x[b,t,:] @ Wx + bias  -> f16 in d_ws (256 MB).
// Stage 2 (lstm_xg): 128 blocks x 512 thr, one block per batch, NO cross-block
//   sync (R3/R5 lesson: device-scope handshakes cost ~6 us/step via L3
//   coherence maintenance). Thread tid owns cols (tid, tid+512): {i,g} gates of
//   unit u=tid&255 if tid<256 else {f,o}. Wh f16x2: k in [0,192) in registers
//   (192 VGPRs; 512-thr block @ launch_bounds(512,2) -> 256-VGPR cap, R4
//   lesson), k in [192,256) in LDS ([col][33]-word rows -> bank-spread).
//   h broadcast-read from LDS (same-addr = free). 2 barriers/step.
// Fallbacks: ws < 256MB -> R5 pair kernel; ws tiny -> R2 single-block kernel.

#define Tt 1024
#define Dd 64
#define Hh 256
#define G4 1024
#define Cc 6
#define BT (128 * 1024)

#define XG_BYTES ((size_t)BT * G4 * 2)                 // 256 MB f16
#define WS_NEED_PAIR (1024 + 128*2*2*128*2)

typedef _Float16 f16x2 __attribute__((ext_vector_type(2)));

__device__ __forceinline__ float dot2(f16x2 a, f16x2 b, float c) {
#if __has_builtin(__builtin_amdgcn_fdot2)
    return __builtin_amdgcn_fdot2(a, b, c, false);
#else
    return c + (float)a.x * (float)b.x + (float)a.y * (float)b.y;
#endif
}
__device__ __forceinline__ float sigm(float p) { return 1.0f / (1.0f + __expf(-p)); }
__device__ __forceinline__ float tanh_fast(float p) {
    return 1.0f - 2.0f / (__expf(2.0f * p) + 1.0f);
}
__device__ __forceinline__ unsigned short f2h(float v) {
    _Float16 h = (_Float16)v;
    return __builtin_bit_cast(unsigned short, h);
}
__device__ __forceinline__ float h2f(unsigned short u) {
    return (float)__builtin_bit_cast(_Float16, u);
}

// ---------------- stage 1: xg = x @ Wx + bias, f16 ----------------
__global__ __launch_bounds__(256) void xg_gemm(
    const float* __restrict__ x,      // [BT, 64]
    const float* __restrict__ Wx,     // [64, 1024]
    const float* __restrict__ bias,   // [1024]
    unsigned short* __restrict__ xg)  // [BT, 1024] f16
{
    __shared__ float xs[32][65];      // 32 rows x 64, pad 65 -> conflict-free
    __shared__ float wsl[64][256];    // Wx col-slice, 64 KB

    const int tid = threadIdx.x;
    const long r0 = (long)blockIdx.x * 32;
    const int  c0 = blockIdx.y * 256;

    { // x tile: 2048 floats = 512 float4, thread gets i and i+256
        const float4* src = (const float4*)(x + r0 * Dd);
        float4 v0 = src[tid], v1 = src[tid + 256];
        int e = tid * 4;
        xs[e >> 6][e & 63] = v0.x; xs[e >> 6][(e & 63) + 1] = v0.y;
        xs[e >> 6][(e & 63) + 2] = v0.z; xs[e >> 6][(e & 63) + 3] = v0.w;
        e += 1024;
        xs[e >> 6][e & 63] = v1.x; xs[e >> 6][(e & 63) + 1] = v1.y;
        xs[e >> 6][(e & 63) + 2] = v1.z; xs[e >> 6][(e & 63) + 3] = v1.w;
    }
    for (int i = tid; i < 64 * 64; i += 256) {  // Wx slice in float4 units
        int d = i >> 6, cq = i & 63;
        *(float4*)&wsl[d][cq * 4] = *(const float4*)(Wx + (long)d * G4 + c0 + cq * 4);
    }
    __syncthreads();

    const int r = tid & 31, cg = tid >> 5;      // row 0..31, col-group 0..7
    float acc[32];
    #pragma unroll
    for (int c = 0; c < 32; ++c) acc[c] = bias[c0 + cg * 32 + c];
    for (int k = 0; k < 64; ++k) {
        float xv = xs[r][k];
        #pragma unroll
        for (int c = 0; c < 32; ++c) acc[c] += xv * wsl[k][cg * 32 + c];
    }
    unsigned int ow[16];
    #pragma unroll
    for (int c2 = 0; c2 < 16; ++c2)
        ow[c2] = (unsigned int)f2h(acc[2 * c2]) | ((unsigned int)f2h(acc[2 * c2 + 1]) << 16);
    uint4* dst = (uint4*)(xg + (r0 + r) * G4 + c0 + cg * 32);
    dst[0] = make_uint4(ow[0], ow[1], ow[2], ow[3]);
    dst[1] = make_uint4(ow[4], ow[5], ow[6], ow[7]);
    dst[2] = make_uint4(ow[8], ow[9], ow[10], ow[11]);
    dst[3] = make_uint4(ow[12], ow[13], ow[14], ow[15]);
}

// ---------------- stage 2: recurrence, one block per batch ----------------
#define KREG 192            // k in [0,192) from registers (96 f16x2 per col)
#define KLDSP 32            // 32 f16x2 pairs (k 192..255) per col in LDS

__global__ __launch_bounds__(512, 2) void lstm_xg(
    const unsigned short* __restrict__ xg,  // [B,T,1024] f16, bias folded
    const float* __restrict__ Wh,           // [H, 4H]
    const float* __restrict__ Wout,         // [H, C]
    const float* __restrict__ bout,         // [C]
    float* __restrict__ out)                // [B,T,C]
{
    __shared__ unsigned short h_f16[Hh];        // current h, f16
    __shared__ float gl[2][Hh];                 // f,o published by hi threads
    __shared__ float wout_t[Cc][Hh];
    __shared__ float bout_l[8];
    __shared__ f16x2 wlds[G4][33];              // Wh k in [192,256): 132 KB

    const int tid  = threadIdx.x;
    const int b    = blockIdx.x;
    const int col0 = tid;                       // i (tid<256) or f
    const int col1 = tid + 512;                 // g (tid<256) or o
    const bool lo  = tid < 256;                 // wave-uniform

    // ---- prologue: Wh -> 192 f16x2 registers + LDS tail ----
    f16x2 wh0[96], wh1[96];
    #pragma unroll
    for (int j = 0; j < 96; ++j) {
        wh0[j] = f16x2{(_Float16)Wh[(2 * j) * G4 + col0],
                       (_Float16)Wh[(2 * j + 1) * G4 + col0]};
        wh1[j] = f16x2{(_Float16)Wh[(2 * j) * G4 + col1],
                       (_Float16)Wh[(2 * j + 1) * G4 + col1]};
    }
    #pragma unroll
    for (int j = 0; j < KLDSP; ++j) {
        wlds[col0][j] = f16x2{(_Float16)Wh[(KREG + 2 * j) * G4 + col0],
                              (_Float16)Wh[(KREG + 2 * j + 1) * G4 + col0]};
        wlds[col1][j] = f16x2{(_Float16)Wh[(KREG + 2 * j) * G4 + col1],
                              (_Float16)Wh[(KREG + 2 * j + 1) * G4 + col1]};
    }
    if (tid < Hh) h_f16[tid] = 0;
    for (int i = tid; i < Cc * Hh; i += 512) wout_t[i % Cc][i / Cc] = Wout[i];
    if (tid < Cc) bout_l[tid] = bout[tid];

    const unsigned short* xgB = xg + (long)b * Tt * G4;
    unsigned short xgv0 = xgB[col0], xgv1 = xgB[col1];   // t = 0
    float c_state = 0.0f;
    __syncthreads();

    // ---- time loop ----
    for (int t = 0; t < Tt; ++t) {
        // prefetch next xg early (latency hides under dots)
        unsigned short nxg0 = 0, nxg1 = 0;
        if (t + 1 < Tt) {
            nxg0 = xgB[(long)(t + 1) * G4 + col0];
            nxg1 = xgB[(long)(t + 1) * G4 + col1];
        }

        // phase A: full-K dots for 2 cols (no cross-lane reduction needed)
        float a0 = 0.0f, a1 = 0.0f;
        const f16x2* hv = (const f16x2*)h_f16;   // broadcast reads (free)
        #pragma unroll
        for (int j = 0; j < 96; ++j) {
            f16x2 h2 = hv[j];
            a0 = dot2(h2, wh0[j], a0);
            a1 = dot2(h2, wh1[j], a1);
        }
        const f16x2* w0p = wlds[col0];
        const f16x2* w1p = wlds[col1];
        #pragma unroll
        for (int j = 0; j < KLDSP; ++j) {
            f16x2 h2 = hv[96 + j];
            a0 = dot2(h2, w0p[j], a0);
            a1 = dot2(h2, w1p[j], a1);
        }

        float pre0 = h2f(xgv0) + a0;    // bias already folded into xg
        float pre1 = h2f(xgv1) + a1;
        float r0a, r1a;
        if (lo) { r0a = sigm(pre0); r1a = tanh_fast(pre1); }  // i, g
        else    { r0a = sigm(pre0); r1a = sigm(pre1); }       // f, o

        const int u = tid & 255;
        if (!lo) { gl[0][u] = r0a; gl[1][u] = r1a; }          // publish f,o
        __syncthreads();  // B1: gates ready; all h reads done

        if (lo) {
            float fv = gl[0][u], ov = gl[1][u];
            c_state = fv * c_state + r0a * r1a;               // i*g
            float hval = ov * tanh_fast(c_state);
            h_f16[u] = f2h(hval);
        }
        __syncthreads();  // B2: h(t) staged

        // phase C: output projection (waves 0..5), overlaps next step's dots
        const int w = tid >> 6, l = tid & 63;
        if (w < Cc) {
            float p = 0.0f;
            #pragma unroll
            for (int j = 0; j < 4; ++j)
                p += h2f(h_f16[l + 64 * j]) * wout_t[w][l + 64 * j];
            #pragma unroll
            for (int off = 32; off > 0; off >>= 1) p += __shfl_down(p, off);
            if (l == 0) out[((long)b * Tt + t) * Cc + w] = p + bout_l[w];
        }

        xgv0 = nxg0; xgv1 = nxg1;
    }
}

// ---------------- fallback A: R5 pair kernel (ws >= 132 KB) ----------------
__global__ void zero_flags(int* flags) {
    if (threadIdx.x < 256) flags[threadIdx.x] = 0;
}

__global__ __launch_bounds__(512, 2) void lstm_pair(
    const float* __restrict__ x, const float* __restrict__ Wx,
    const float* __restrict__ Wh, const float* __restrict__ bias,
    const float* __restrict__ Wout, const float* __restrict__ bout,
    float* __restrict__ out, int* __restrict__ flags,
    unsigned short* __restrict__ hx)
{
    __shared__ alignas(16) unsigned short h_lds[4][72];
    __shared__ alignas(16) unsigned short x_lds[2][4][24];
    __shared__ float wout_t[Cc][Hh];
    __shared__ float bout_l[Cc];

    const int tid  = threadIdx.x;
    const int bid  = blockIdx.x;
    const int xcd  = bid & 7;
    const int slot = bid >> 3;
    const int half = slot & 1;
    const int g    = xcd * 16 + (slot >> 1);

    const int u_loc = tid >> 2;
    const int ks    = tid & 3;
    const int u     = 128 * half + u_loc;

    int* flg = flags + g * 2;
    unsigned short* hxg = hx + g * 512;

    f16x2 wh[4][32];
    f16x2 wxr[4][8];
    float bq[4];
    #pragma unroll
    for (int q = 0; q < 4; ++q) {
        const int col = 256 * q + u;
        #pragma unroll
        for (int j = 0; j < 32; ++j)
            wh[q][j] = f16x2{(_Float16)Wh[(64 * ks + 2 * j) * G4 + col],
                             (_Float16)Wh[(64 * ks + 2 * j + 1) * G4 + col]};
        #pragma unroll
        for (int j = 0; j < 8; ++j)
            wxr[q][j] = f16x2{(_Float16)Wx[(16 * ks + 2 * j) * G4 + col],
                              (_Float16)Wx[(16 * ks + 2 * j + 1) * G4 + col]};
        bq[q] = bias[col];
    }
    if (tid < 288) ((unsigned short*)h_lds)[tid] = 0;
    for (int i = tid; i < Cc * Hh; i += 512) wout_t[i % Cc][i / Cc] = Wout[i];
    if (tid < Cc) bout_l[tid] = bout[tid];
    const float* xB = x + (long)g * Tt * Dd;
    if (tid >= 448) {
        int d = tid - 448;
        x_lds[0][d >> 4][d & 15] = f2h(xB[d]);
    }
    float c_state = 0.0f;
    __syncthreads();

    for (int t = 0; t < Tt; ++t) {
        const int par = t & 1;
        float x_next = 0.0f;
        const bool xload = (tid >= 448) && (t + 1 < Tt);
        if (xload) x_next = xB[(long)(t + 1) * Dd + (tid - 448)];

        float a0 = 0.f, a1 = 0.f, a2 = 0.f, a3 = 0.f;
        {
            const float4* hq = (const float4*)((const char*)h_lds + 144 * ks);
            #pragma unroll
            for (int j = 0; j < 8; ++j) {
                float4 hvv = hq[j];
                f16x2 h0 = __builtin_bit_cast(f16x2, hvv.x);
                f16x2 h1 = __builtin_bit_cast(f16x2, hvv.y);
                f16x2 h2 = __builtin_bit_cast(f16x2, hvv.z);
                f16x2 h3 = __builtin_bit_cast(f16x2, hvv.w);
                a0 = dot2(h0, wh[0][4*j+0], a0); a0 = dot2(h1, wh[0][4*j+1], a0);
                a0 = dot2(h2, wh[0][4*j+2], a0); a0 = dot2(h3, wh[0][4*j+3], a0);
                a1 = dot2(h0, wh[1][4*j+0], a1); a1 = dot2(h1, wh[1][4*j+1], a1);
                a1 = dot2(h2, wh[1][4*j+2], a1); a1 = dot2(h3, wh[1][4*j+3], a1);
                a2 = dot2(h0, wh[2][4*j+0], a2); a2 = dot2(h1, wh[2][4*j+1], a2);
                a2 = dot2(h2, wh[2][4*j+2], a2); a2 = dot2(h3, wh[2][4*j+3], a2);
                a3 = dot2(h0, wh[3][4*j+0], a3); a3 = dot2(h1, wh[3][4*j+1], a3);
                a3 = dot2(h2, wh[3][4*j+2], a3); a3 = dot2(h3, wh[3][4*j+3], a3);
            }
            const float4* xq = (const float4*)((const char*)x_lds[par] + 48 * ks);
            #pragma unroll
            for (int j = 0; j < 2; ++j) {
                float4 xv = xq[j];
                f16x2 x0 = __builtin_bit_cast(f16x2, xv.x);
                f16x2 x1 = __builtin_bit_cast(f16x2, xv.y);
                f16x2 x2 = __builtin_bit_cast(f16x2, xv.z);
                f16x2 x3 = __builtin_bit_cast(f16x2, xv.w);
                a0 = dot2(x0, wxr[0][4*j+0], a0); a0 = dot2(x1, wxr[0][4*j+1], a0);
                a0 = dot2(x2, wxr[0][4*j+2], a0); a0 = dot2(x3, wxr[0][4*j+3], a0);
                a1 = dot2(x0, wxr[1][4*j+0], a1); a1 = dot2(x1, wxr[1][4*j+1], a1);
                a1 = dot2(x2, wxr[1][4*j+2], a1); a1 = dot2(x3, wxr[1][4*j+3], a1);
                a2 = dot2(x0, wxr[2][4*j+0], a2); a2 = dot2(x1, wxr[2][4*j+1], a2);
                a2 = dot2(x2, wxr[2][4*j+2], a2); a2 = dot2(x3, wxr[2][4*j+3], a2);
                a3 = dot2(x0, wxr[3][4*j+0], a3); a3 = dot2(x1, wxr[3][4*j+1], a3);
                a3 = dot2(x2, wxr[3][4*j+2], a3); a3 = dot2(x3, wxr[3][4*j+3], a3);
            }
        }
        a0 += __shfl_xor(a0, 1); a0 += __shfl_xor(a0, 2);
        a1 += __shfl_xor(a1, 1); a1 += __shfl_xor(a1, 2);
        a2 += __shfl_xor(a2, 1); a2 += __shfl_xor(a2, 2);
        a3 += __shfl_xor(a3, 1); a3 += __shfl_xor(a3, 2);

        float ig = sigm(a0 + bq[0]);
        float fg = sigm(a1 + bq[1]);
        float gg = tanh_fast(a2 + bq[2]);
        float og = sigm(a3 + bq[3]);
        c_state = fg * c_state + ig * gg;
        float hval = og * tanh_fast(c_state);

        unsigned int hbits = (unsigned int)f2h(hval);
        unsigned int hpair = hbits | (__shfl_down((int)hbits, 4) << 16);
        if ((tid & 7) == 0) {
            unsigned int* dst = (unsigned int*)(hxg + par * 256 + half * 128);
            __hip_atomic_store(&dst[u_loc >> 1], hpair,
                               __ATOMIC_RELAXED, __HIP_MEMORY_SCOPE_AGENT);
        }
        __syncthreads();

        if (tid == 0) {
            __hip_atomic_fetch_add(&flg[par], 1, __ATOMIC_RELEASE, __HIP_MEMORY_SCOPE_AGENT);
            const int target = 2 * ((t >> 1) + 1);
            for (int spin = 0; spin < (1 << 26); ++spin) {
                if (__hip_atomic_load(&flg[par], __ATOMIC_ACQUIRE,
                                      __HIP_MEMORY_SCOPE_AGENT) >= target) break;
                __builtin_amdgcn_s_sleep(1);
            }
        }
        __syncthreads();

        if (ks == 0) h_lds[u >> 6][u & 63] = (unsigned short)hbits;
        if (tid < 64) {
            const unsigned int* src = (const unsigned int*)(hxg + par * 256 + (half ^ 1) * 128);
            unsigned int v = __hip_atomic_load(&src[tid],
                                               __ATOMIC_RELAXED, __HIP_MEMORY_SCOPE_AGENT);
            int up = 128 * (half ^ 1) + 2 * tid;
            *(unsigned int*)&h_lds[up >> 6][up & 63] = v;
        }
        if (xload) {
            int d = tid - 448;
            x_lds[(t + 1) & 1][d >> 4][d & 15] = f2h(x_next);
        }
        __syncthreads();

        if (half == 0) {
            const int w = tid >> 6, l = tid & 63;
            if (w < Cc) {
                float p = 0.0f;
                #pragma unroll
                for (int j = 0; j < 4; ++j)
                    p += h2f(h_lds[j][l]) * wout_t[w][l + 64 * j];
                #pragma unroll
                for (int off = 32; off > 0; off >>= 1) p += __shfl_down(p, off);
                if (l == 0) out[((long)g * Tt + t) * Cc + w] = p + bout_l[w];
            }
        }
    }
}

// ---------------- fallback B: R2 single-block kernel ----------------
__global__ __launch_bounds__(1024) void lstm_fused(
    const float* __restrict__ x, const float* __restrict__ Wx,
    const float* __restrict__ Wh, const float* __restrict__ bias,
    const float* __restrict__ Wout, const float* __restrict__ bout,
    float* __restrict__ out)
{
    __shared__ float h_lds[Hh];
    __shared__ float gates_lds[G4];
    __shared__ float x_lds[2][Dd];
    __shared__ float wout_t[Cc][Hh];
    __shared__ float bout_l[Cc];
    const int tid = threadIdx.x;
    const int b   = blockIdx.x;
    float wx[Dd];
    #pragma unroll
    for (int d = 0; d < Dd; ++d) wx[d] = Wx[d * G4 + tid];
    const float bj = bias[tid];
    if (tid < Hh) h_lds[tid] = 0.0f;
    for (int i = tid; i < Cc * Hh; i += 1024) wout_t[i % Cc][i / Cc] = Wout[i];
    if (tid < Cc) bout_l[tid] = bout[tid];
    const float* xB = x + (long)b * Tt * Dd;
    if (tid < Dd) x_lds[0][tid] = xB[tid];
    float c_state = 0.0f;
    __syncthreads();
    const float* WhB = Wh + tid;
    for (int t = 0; t < Tt; ++t) {
        float gg = bj;
        const float* xr = x_lds[t & 1];
        #pragma unroll
        for (int d = 0; d < Dd; ++d) gg += xr[d] * wx[d];
        #pragma unroll 8
        for (int k = 0; k < Hh; ++k) gg += h_lds[k] * WhB[k * G4];
        float a;
        if (tid < 2 * Hh)      a = 1.0f / (1.0f + expf(-gg));
        else if (tid < 3 * Hh) a = tanhf(gg);
        else                   a = 1.0f / (1.0f + expf(-gg));
        gates_lds[tid] = a;
        __syncthreads();
        if (tid < Hh) {
            float iv = gates_lds[tid], fv = gates_lds[tid + Hh];
            float gv = gates_lds[tid + 2 * Hh], ov = gates_lds[tid + 3 * Hh];
            c_state = fv * c_state + iv * gv;
            h_lds[tid] = ov * tanhf(c_state);
        } else if (tid >= 384 && tid < 448) {
            int tn = t + 1;
            if (tn < Tt) x_lds[tn & 1][tid - 384] = xB[(long)tn * Dd + (tid - 384)];
        }
        __syncthreads();
        const int w = tid >> 6, l = tid & 63;
        if (w < Cc) {
            float p = 0.0f;
            #pragma unroll
            for (int qq = 0; qq < 4; ++qq) p += h_lds[l + 64 * qq] * wout_t[w][l + 64 * qq];
            #pragma unroll
            for (int off = 32; off > 0; off >>= 1) p += __shfl_down(p, off);
            if (l == 0) out[((long)b * Tt + t) * Cc + w] = p + bout_l[w];
        }
    }
}

extern "C" void kernel_launch(void* const* d_in, const int* in_sizes, int n_in,
                              void* d_out, int out_size, void* d_ws, size_t ws_size,
                              hipStream_t stream) {
    const float* x    = (const float*)d_in[0];
    const float* Wx   = (const float*)d_in[1];
    const float* Wh   = (const float*)d_in[2];
    const float* bvec = (const float*)d_in[3];
    const float* Wout = (const float*)d_in[4];
    const float* bout = (const float*)d_in[5];
    float* outp = (float*)d_out;

    if (ws_size >= XG_BYTES) {
        unsigned short* xgws = (unsigned short*)d_ws;
        xg_gemm<<<dim3(BT / 32, 4), dim3(256), 0, stream>>>(x, Wx, bvec, xgws);
        lstm_xg<<<dim3(128), dim3(512), 0, stream>>>(xgws, Wh, Wout, bout, outp);
    } else if (ws_size >= (size_t)WS_NEED_PAIR) {
        int* flags = (int*)d_ws;
        unsigned short* hx = (unsigned short*)((char*)d_ws + 1024);
        zero_flags<<<dim3(1), dim3(256), 0, stream>>>(flags);
        void* args[] = { (void*)&x, (void*)&Wx, (void*)&Wh, (void*)&bvec,
                         (void*)&Wout, (void*)&bout, (void*)&outp,
                         (void*)&flags, (void*)&hx };
        hipLaunchCooperativeKernel((void*)lstm_pair, dim3(256), dim3(512),
                                   args, 0, stream);
    } else {
        lstm_fused<<<dim3(128), dim3(1024), 0, stream>>>(x, Wx, Wh, bvec, Wout, bout, outp);
    }
}